// Round 5
// baseline (242.689 us; speedup 1.0000x reference)
//
#include <hip/hip_runtime.h>

// VectorQuantizer forward, MI355X — MFMA bf16-split distance path.
// x:     [32, 64, 64, 64] f32  (B, C=D, H, W)
// embed: [1024, 64] f32
// out:   quantized [32,64,64,64] flat (8388608 floats) ++ loss (1 float)

#define NE    1024
#define DD    64
#define HWSZ  4096
#define NB    32
#define NROW  (NB * HWSZ)        // 131072 rows
#define BLK   256
#define NELEM (NB * DD * HWSZ)   // 8388608
#define KTILE 128                // fallback path tile

typedef __attribute__((ext_vector_type(8))) short short8v;   // 8 bf16
typedef __attribute__((ext_vector_type(4))) float f32x4;

// workspace layout (bytes)
#define WS_ACC  0
#define WS_EE   1024                      // 1024 f32
#define WS_EHI  8192                      // 1024*64 bf16 = 131072 B
#define WS_EMID (8192 + 131072)
#define WS_ELO  (8192 + 2 * 131072)
#define WS_XX   (8192 + 3 * 131072)       // 131072 f32 = 524288 B
#define WS_BI   (WS_XX + 524288)          // 131072 i32
#define WS_NEED ((size_t)(WS_BI + 524288))

__device__ __forceinline__ ushort f2bf(float f) {           // f32 -> bf16 RNE
    union { float f; unsigned u; } v; v.f = f;
    unsigned r = v.u + 0x7fffu + ((v.u >> 16) & 1u);
    return (ushort)(r >> 16);
}
__device__ __forceinline__ float bf2f(ushort h) {
    union { unsigned u; float f; } v; v.u = ((unsigned)h) << 16;
    return v.f;
}

// -------- init: ||e||^2 (ref order) + 3-way bf16 split of E + zero acc ------
__global__ void vq_init2(const float* __restrict__ embed, float* __restrict__ ee,
                         ushort* __restrict__ ehi, ushort* __restrict__ emid,
                         ushort* __restrict__ elo, double* __restrict__ acc) {
    int k = blockIdx.x * blockDim.x + threadIdx.x;
    if (k == 0) *acc = 0.0;
    if (k < NE) {
        const float* e = embed + k * DD;
        float s = 0.f;
        for (int d = 0; d < DD; ++d) {
            float v = e[d];
            s = __fadd_rn(s, __fmul_rn(v, v));   // mimic ref sum(e**2)
            ushort h = f2bf(v);  float fh = bf2f(h);
            float r1 = v - fh;   ushort m = f2bf(r1); float fm = bf2f(m);
            float r2 = r1 - fm;  ushort l = f2bf(r2);
            ehi[k * DD + d] = h; emid[k * DD + d] = m; elo[k * DD + d] = l;
        }
        ee[k] = s;
    }
}

// -------- ||x||^2 per row (ref order, coalesced) ----------------------------
__global__ __launch_bounds__(BLK) void vq_xx(const float* __restrict__ x,
                                             float* __restrict__ xx) {
    int r = blockIdx.x * BLK + threadIdx.x;
    int b = r >> 12, hw = r & (HWSZ - 1);
    const float* xb = x + (size_t)b * (DD * HWSZ) + hw;
    float s = 0.f;
    #pragma unroll
    for (int d = 0; d < DD; ++d) {
        float v = xb[(size_t)d * HWSZ];
        s = __fadd_rn(s, __fmul_rn(v, v));       // mimic ref sum(x**2)
    }
    xx[r] = s;
}

// -------- MFMA distance + argmin: one wave = 32 rows x all 1024 codes -------
// 4096 waves -> 16 waves/CU (4/SIMD) for latency hiding; <=128 VGPR enforced.
__global__ __launch_bounds__(BLK, 4) void vq_dist_mfma(
    const float* __restrict__ x,
    const ushort* __restrict__ ehi, const ushort* __restrict__ emid,
    const ushort* __restrict__ elo, const float* __restrict__ ee,
    const float* __restrict__ xx, int* __restrict__ bestI)
{
    const int lane = threadIdx.x & 63;
    const int wid  = threadIdx.x >> 6;
    const int wg   = blockIdx.x * 4 + wid;   // 0..4095
    const int r0   = wg * 32;                // 32 rows per wave
    const int col  = lane & 15;              // A-row / B-col / C-col lane slot
    const int grp  = lane >> 4;              // 0..3 (k-group / C row-group)
    const int d0   = grp * 8;

    // A fragments: 2 row-tiles x {hi,mid,lo} x 2 k-slices, split on the fly
    short8v a_hi[2][2], a_mid[2][2], a_lo[2][2];
    float   xxv[2][4];

    #pragma unroll
    for (int rt = 0; rt < 2; ++rt) {
        int r = r0 + rt * 16 + col;
        int b = r >> 12, hw = r & (HWSZ - 1);
        const float* xb = x + (size_t)b * (DD * HWSZ) + hw;
        #pragma unroll
        for (int ks = 0; ks < 2; ++ks) {
            short8v vh, vm, vl;
            #pragma unroll
            for (int j = 0; j < 8; ++j) {
                float v = xb[(size_t)(ks * 32 + d0 + j) * HWSZ];
                ushort h = f2bf(v);  float fh = bf2f(h);
                float r1 = v - fh;   ushort m = f2bf(r1); float fm = bf2f(m);
                float r2 = r1 - fm;  ushort l = f2bf(r2);
                vh[j] = (short)h; vm[j] = (short)m; vl[j] = (short)l;
            }
            a_hi[rt][ks] = vh; a_mid[rt][ks] = vm; a_lo[rt][ks] = vl;
        }
        #pragma unroll
        for (int q = 0; q < 4; ++q)
            xxv[rt][q] = xx[r0 + rt * 16 + grp * 4 + q];
    }

    float bD[2][4]; int bI[2][4];
    #pragma unroll
    for (int rt = 0; rt < 2; ++rt)
        #pragma unroll
        for (int q = 0; q < 4; ++q) { bD[rt][q] = 3.4e38f; bI[rt][q] = 0; }

    for (int ct = 0; ct < NE / 16; ++ct) {
        // B fragments: lane reads 8 contiguous bf16 of code (ct*16+col)
        const size_t eb = ((size_t)(ct * 16 + col)) * DD + d0;
        short8v bh0 = *(const short8v*)(ehi  + eb);
        short8v bh1 = *(const short8v*)(ehi  + eb + 32);
        short8v bm0 = *(const short8v*)(emid + eb);
        short8v bm1 = *(const short8v*)(emid + eb + 32);
        short8v bl0 = *(const short8v*)(elo  + eb);
        short8v bl1 = *(const short8v*)(elo  + eb + 32);
        float eev = ee[ct * 16 + col];

        #pragma unroll
        for (int rt = 0; rt < 2; ++rt) {
            f32x4 acc = {0.f, 0.f, 0.f, 0.f};
            // 6-pass split: hi*hi + hi*mid + mid*hi + hi*lo + lo*hi + mid*mid
            acc = __builtin_amdgcn_mfma_f32_16x16x32_bf16(a_hi[rt][0],  bh0, acc, 0, 0, 0);
            acc = __builtin_amdgcn_mfma_f32_16x16x32_bf16(a_hi[rt][1],  bh1, acc, 0, 0, 0);
            acc = __builtin_amdgcn_mfma_f32_16x16x32_bf16(a_hi[rt][0],  bm0, acc, 0, 0, 0);
            acc = __builtin_amdgcn_mfma_f32_16x16x32_bf16(a_hi[rt][1],  bm1, acc, 0, 0, 0);
            acc = __builtin_amdgcn_mfma_f32_16x16x32_bf16(a_mid[rt][0], bh0, acc, 0, 0, 0);
            acc = __builtin_amdgcn_mfma_f32_16x16x32_bf16(a_mid[rt][1], bh1, acc, 0, 0, 0);
            acc = __builtin_amdgcn_mfma_f32_16x16x32_bf16(a_hi[rt][0],  bl0, acc, 0, 0, 0);
            acc = __builtin_amdgcn_mfma_f32_16x16x32_bf16(a_hi[rt][1],  bl1, acc, 0, 0, 0);
            acc = __builtin_amdgcn_mfma_f32_16x16x32_bf16(a_lo[rt][0],  bh0, acc, 0, 0, 0);
            acc = __builtin_amdgcn_mfma_f32_16x16x32_bf16(a_lo[rt][1],  bh1, acc, 0, 0, 0);
            acc = __builtin_amdgcn_mfma_f32_16x16x32_bf16(a_mid[rt][0], bm0, acc, 0, 0, 0);
            acc = __builtin_amdgcn_mfma_f32_16x16x32_bf16(a_mid[rt][1], bm1, acc, 0, 0, 0);
            #pragma unroll
            for (int q = 0; q < 4; ++q) {
                // dist = rn(rn(xx+ee) - 2*dot): fma is exact for *(-2)
                float t1 = __fadd_rn(xxv[rt][q], eev);
                float di = fmaf(acc[q], -2.f, t1);
                int idx = ct * 16 + col;
                if (di < bD[rt][q]) { bD[rt][q] = di; bI[rt][q] = idx; }
            }
        }
    }

    // cross-lane argmin over the 16 col-classes in each row-group
    #pragma unroll
    for (int rt = 0; rt < 2; ++rt) {
        #pragma unroll
        for (int q = 0; q < 4; ++q) {
            float d = bD[rt][q]; int i = bI[rt][q];
            #pragma unroll
            for (int off = 1; off < 16; off <<= 1) {
                float od = __shfl_xor(d, off, 64);
                int   oi = __shfl_xor(i, off, 64);
                if (od < d || (od == d && oi < i)) { d = od; i = oi; }
            }
            if (col == 0) bestI[r0 + rt * 16 + grp * 4 + q] = i;
        }
    }
}

// -------- gather winning code, write transposed out, accumulate loss --------
__global__ __launch_bounds__(BLK) void vq_out(
    const float* __restrict__ x, const float* __restrict__ embed,
    const int* __restrict__ bestI, float* __restrict__ out,
    double* __restrict__ lossAcc)
{
    __shared__ float partial[BLK / 64];
    const int t = threadIdx.x;
    const int r = blockIdx.x * BLK + t;
    const int bi = bestI[r];
    const int b = r >> 12, hw = r & (HWSZ - 1);
    const float* xb = x   + (size_t)b * (DD * HWSZ) + hw;
    float*       ob = out + (size_t)b * (DD * HWSZ) + hw;
    const float4* eq = (const float4*)(embed + (size_t)bi * DD);

    float lsum = 0.f;
    #pragma unroll
    for (int c4 = 0; c4 < DD / 4; ++c4) {
        float4 q = eq[c4];
        float qa[4] = {q.x, q.y, q.z, q.w};
        #pragma unroll
        for (int i2 = 0; i2 < 4; ++i2) {
            int c = c4 * 4 + i2;
            float xv = xb[(size_t)c * HWSZ];
            ob[(size_t)c * HWSZ] = qa[i2];
            float f = qa[i2] - xv;
            lsum = fmaf(f, f, lsum);
        }
    }
    for (int off = 32; off > 0; off >>= 1) lsum += __shfl_down(lsum, off, 64);
    if ((t & 63) == 0) partial[t >> 6] = lsum;
    __syncthreads();
    if (t == 0) {
        float tot = 0.f;
        #pragma unroll
        for (int w = 0; w < BLK / 64; ++w) tot += partial[w];
        atomicAdd(lossAcc, (double)tot);
    }
}

// -------- fallback single kernel (small ws) ---------------------------------
__global__ __launch_bounds__(BLK) void vq_main_single(
    const float* __restrict__ x, const float* __restrict__ embed,
    const float* __restrict__ e2, float* __restrict__ out,
    double* __restrict__ lossAcc)
{
    __shared__ float lds_e[KTILE * DD];
    const int t   = threadIdx.x;
    const int b   = blockIdx.x >> 3;
    const int hw0 = (blockIdx.x & 7) * (2 * BLK);
    const float* xb = x + (size_t)b * (DD * HWSZ);
    const int hwa = hw0 + t, hwb = hw0 + t + BLK;

    float xr0[DD], xr1[DD];
    float xx0 = 0.f, xx1 = 0.f;
    #pragma unroll
    for (int c = 0; c < DD; ++c) {
        float v0 = xb[(size_t)c * HWSZ + hwa];
        float v1 = xb[(size_t)c * HWSZ + hwb];
        xr0[c] = v0; xr1[c] = v1;
        xx0 = __fadd_rn(xx0, __fmul_rn(v0, v0));
        xx1 = __fadd_rn(xx1, __fmul_rn(v1, v1));
    }
    float best0 = 3.4e38f, best1 = 3.4e38f;
    int bi0 = 0, bi1 = 0;
    for (int k0 = 0; k0 < NE; k0 += KTILE) {
        __syncthreads();
        const float4* src = reinterpret_cast<const float4*>(embed + k0 * DD);
        float4* dst = reinterpret_cast<float4*>(lds_e);
        #pragma unroll
        for (int j = 0; j < (KTILE * DD / 4) / BLK; ++j)
            dst[t + j * BLK] = src[t + j * BLK];
        __syncthreads();
        for (int c = 0; c < KTILE; ++c) {
            float ee = e2[k0 + c];
            const float* ev = &lds_e[c * DD];
            float a0 = 0.f, a1 = 0.f;
            #pragma unroll
            for (int d = 0; d < DD; ++d) {
                float e = ev[d];
                a0 = fmaf(e, xr0[d], a0);
                a1 = fmaf(e, xr1[d], a1);
            }
            float di0 = __fadd_rn(__fadd_rn(xx0, ee), -2.f * a0);
            float di1 = __fadd_rn(__fadd_rn(xx1, ee), -2.f * a1);
            int kk = k0 + c;
            if (di0 < best0) { best0 = di0; bi0 = kk; }
            if (di1 < best1) { best1 = di1; bi1 = kk; }
        }
    }
    float lsum = 0.f;
    {
        const float4* eq0 = reinterpret_cast<const float4*>(embed + bi0 * DD);
        const float4* eq1 = reinterpret_cast<const float4*>(embed + bi1 * DD);
        float* ob = out + (size_t)b * (DD * HWSZ);
        #pragma unroll
        for (int c4 = 0; c4 < DD / 4; ++c4) {
            float4 q0 = eq0[c4];
            float4 q1 = eq1[c4];
            float q0a[4] = {q0.x, q0.y, q0.z, q0.w};
            float q1a[4] = {q1.x, q1.y, q1.z, q1.w};
            #pragma unroll
            for (int i = 0; i < 4; ++i) {
                int c = c4 * 4 + i;
                ob[(size_t)c * HWSZ + hwa] = q0a[i];
                ob[(size_t)c * HWSZ + hwb] = q1a[i];
                float f0 = q0a[i] - xr0[c];
                float f1 = q1a[i] - xr1[c];
                lsum = fmaf(f0, f0, lsum);
                lsum = fmaf(f1, f1, lsum);
            }
        }
    }
    for (int off = 32; off > 0; off >>= 1)
        lsum += __shfl_down(lsum, off, 64);
    __syncthreads();
    if ((t & 63) == 0) lds_e[t >> 6] = lsum;
    __syncthreads();
    if (t == 0) {
        float tot = lds_e[0] + lds_e[1] + lds_e[2] + lds_e[3];
        atomicAdd(lossAcc, (double)tot);
    }
}

// -------- finalize ----------------------------------------------------------
__global__ void vq_fin(const double* __restrict__ acc, float* __restrict__ out) {
    out[NELEM] = (float)(1.25 * (*acc) / (double)NELEM);
}

extern "C" void kernel_launch(void* const* d_in, const int* in_sizes, int n_in,
                              void* d_out, int out_size, void* d_ws, size_t ws_size,
                              hipStream_t stream) {
    const float* x     = (const float*)d_in[0];
    const float* embed = (const float*)d_in[1];
    float* out = (float*)d_out;

    double* acc  = (double*)((char*)d_ws + WS_ACC);
    float*  ee   = (float*)((char*)d_ws + WS_EE);
    ushort* ehi  = (ushort*)((char*)d_ws + WS_EHI);
    ushort* emid = (ushort*)((char*)d_ws + WS_EMID);
    ushort* elo  = (ushort*)((char*)d_ws + WS_ELO);
    float*  xxw  = (float*)((char*)d_ws + WS_XX);
    int*    bIw  = (int*)((char*)d_ws + WS_BI);

    if (ws_size >= WS_NEED) {
        vq_init2<<<(NE + BLK - 1) / BLK, BLK, 0, stream>>>(embed, ee, ehi, emid, elo, acc);
        vq_xx<<<NROW / BLK, BLK, 0, stream>>>(x, xxw);
        vq_dist_mfma<<<NROW / 128, BLK, 0, stream>>>(x, ehi, emid, elo, ee, xxw, bIw);
        vq_out<<<NROW / BLK, BLK, 0, stream>>>(x, embed, bIw, out, acc);
    } else {
        vq_init2<<<(NE + BLK - 1) / BLK, BLK, 0, stream>>>(embed, ee, ehi, emid, elo, acc);
        vq_main_single<<<NB * (HWSZ / (2 * BLK)), BLK, 0, stream>>>(x, embed, ee, out, acc);
    }
    vq_fin<<<1, 1, 0, stream>>>(acc, out);
}

// Round 6
// 158.131 us; speedup vs baseline: 1.5347x; 1.5347x over previous
//
#include <hip/hip_runtime.h>

// VectorQuantizer forward, MI355X — MFMA bf16-split distance path.
// x:     [32, 64, 64, 64] f32  (B, C=D, H, W)
// embed: [1024, 64] f32
// out:   quantized [32,64,64,64] flat (8388608 floats) ++ loss (1 float)

#define NE    1024
#define DD    64
#define HWSZ  4096
#define NB    32
#define NROW  (NB * HWSZ)        // 131072 rows
#define BLK   256
#define NELEM (NB * DD * HWSZ)   // 8388608
#define KTILE 128                // fallback path tile

typedef __attribute__((ext_vector_type(8))) short short8v;   // 8 bf16
typedef __attribute__((ext_vector_type(4))) float f32x4;

// workspace layout (bytes)
#define WS_ACC  0
#define WS_EE   1024                      // 1024 f32
#define WS_EHI  8192                      // 1024*64 bf16 = 131072 B
#define WS_EMID (8192 + 131072)
#define WS_ELO  (8192 + 2 * 131072)
#define WS_XX   (8192 + 3 * 131072)       // 131072 f32 = 524288 B
#define WS_BI   (WS_XX + 524288)          // 131072 i32
#define WS_NEED ((size_t)(WS_BI + 524288))

__device__ __forceinline__ ushort f2bf(float f) {           // f32 -> bf16 RNE
    union { float f; unsigned u; } v; v.f = f;
    unsigned r = v.u + 0x7fffu + ((v.u >> 16) & 1u);
    return (ushort)(r >> 16);
}
__device__ __forceinline__ float bf2f(ushort h) {
    union { unsigned u; float f; } v; v.u = ((unsigned)h) << 16;
    return v.f;
}

// -------- init: ||e||^2 (ref order) + 3-way bf16 split of E + zero acc ------
__global__ void vq_init2(const float* __restrict__ embed, float* __restrict__ ee,
                         ushort* __restrict__ ehi, ushort* __restrict__ emid,
                         ushort* __restrict__ elo, double* __restrict__ acc) {
    int k = blockIdx.x * blockDim.x + threadIdx.x;
    if (k == 0) *acc = 0.0;
    if (k < NE) {
        const float* e = embed + k * DD;
        float s = 0.f;
        for (int d = 0; d < DD; ++d) {
            float v = e[d];
            s = __fadd_rn(s, __fmul_rn(v, v));   // mimic ref sum(e**2)
            ushort h = f2bf(v);  float fh = bf2f(h);
            float r1 = v - fh;   ushort m = f2bf(r1); float fm = bf2f(m);
            float r2 = r1 - fm;  ushort l = f2bf(r2);
            ehi[k * DD + d] = h; emid[k * DD + d] = m; elo[k * DD + d] = l;
        }
        ee[k] = s;
    }
}

// -------- ||x||^2 per row (ref order, coalesced) ----------------------------
__global__ __launch_bounds__(BLK) void vq_xx(const float* __restrict__ x,
                                             float* __restrict__ xx) {
    int r = blockIdx.x * BLK + threadIdx.x;
    int b = r >> 12, hw = r & (HWSZ - 1);
    const float* xb = x + (size_t)b * (DD * HWSZ) + hw;
    float s = 0.f;
    #pragma unroll
    for (int d = 0; d < DD; ++d) {
        float v = xb[(size_t)d * HWSZ];
        s = __fadd_rn(s, __fmul_rn(v, v));       // mimic ref sum(x**2)
    }
    xx[r] = s;
}

struct Bfrag { short8v h0, h1, m0, m1, l0, l1; float ev; };

// -------- MFMA distance + argmin: one wave = 64 rows x all 1024 codes -------
// 2048 waves (grid-limited 2/SIMD); ping-pong B prefetch hides L2 latency.
__global__ __launch_bounds__(BLK, 2) void vq_dist_mfma(
    const float* __restrict__ x,
    const ushort* __restrict__ ehi, const ushort* __restrict__ emid,
    const ushort* __restrict__ elo, const float* __restrict__ ee,
    const float* __restrict__ xx, int* __restrict__ bestI)
{
    const int lane = threadIdx.x & 63;
    const int wid  = threadIdx.x >> 6;
    const int wg   = blockIdx.x * 4 + wid;   // 0..2047
    const int r0   = wg * 64;                // 64 rows per wave
    const int col  = lane & 15;              // A-row / B-col / C-col lane slot
    const int grp  = lane >> 4;              // 0..3 (k-group / C row-group)
    const int d0   = grp * 8;

    // A fragments: 4 row-tiles x {hi,mid,lo} x 2 k-slices, split on the fly
    short8v a_hi[4][2], a_mid[4][2], a_lo[4][2];
    float   xxv[4][4];

    #pragma unroll
    for (int rt = 0; rt < 4; ++rt) {
        int r = r0 + rt * 16 + col;
        int b = r >> 12, hw = r & (HWSZ - 1);
        const float* xb = x + (size_t)b * (DD * HWSZ) + hw;
        #pragma unroll
        for (int ks = 0; ks < 2; ++ks) {
            short8v vh, vm, vl;
            #pragma unroll
            for (int j = 0; j < 8; ++j) {
                float v = xb[(size_t)(ks * 32 + d0 + j) * HWSZ];
                ushort h = f2bf(v);  float fh = bf2f(h);
                float r1 = v - fh;   ushort m = f2bf(r1); float fm = bf2f(m);
                float r2 = r1 - fm;  ushort l = f2bf(r2);
                vh[j] = (short)h; vm[j] = (short)m; vl[j] = (short)l;
            }
            a_hi[rt][ks] = vh; a_mid[rt][ks] = vm; a_lo[rt][ks] = vl;
        }
        #pragma unroll
        for (int q = 0; q < 4; ++q)
            xxv[rt][q] = xx[r0 + rt * 16 + grp * 4 + q];
    }

    float bD[4][4]; int bI[4][4];
    #pragma unroll
    for (int rt = 0; rt < 4; ++rt)
        #pragma unroll
        for (int q = 0; q < 4; ++q) { bD[rt][q] = 3.4e38f; bI[rt][q] = 0; }

    auto loadB = [&](int ct, Bfrag& B) {
        const size_t eb = ((size_t)(ct * 16 + col)) * DD + d0;
        B.h0 = *(const short8v*)(ehi  + eb);
        B.h1 = *(const short8v*)(ehi  + eb + 32);
        B.m0 = *(const short8v*)(emid + eb);
        B.m1 = *(const short8v*)(emid + eb + 32);
        B.l0 = *(const short8v*)(elo  + eb);
        B.l1 = *(const short8v*)(elo  + eb + 32);
        B.ev = ee[ct * 16 + col];
    };

    auto computeTile = [&](const Bfrag& B, int ct) {
        #pragma unroll
        for (int rt = 0; rt < 4; ++rt) {
            f32x4 acc = {0.f, 0.f, 0.f, 0.f};
            // 6-pass split: hi*hi + hi*mid + mid*hi + hi*lo + lo*hi + mid*mid
            acc = __builtin_amdgcn_mfma_f32_16x16x32_bf16(a_hi[rt][0],  B.h0, acc, 0, 0, 0);
            acc = __builtin_amdgcn_mfma_f32_16x16x32_bf16(a_hi[rt][1],  B.h1, acc, 0, 0, 0);
            acc = __builtin_amdgcn_mfma_f32_16x16x32_bf16(a_hi[rt][0],  B.m0, acc, 0, 0, 0);
            acc = __builtin_amdgcn_mfma_f32_16x16x32_bf16(a_hi[rt][1],  B.m1, acc, 0, 0, 0);
            acc = __builtin_amdgcn_mfma_f32_16x16x32_bf16(a_mid[rt][0], B.h0, acc, 0, 0, 0);
            acc = __builtin_amdgcn_mfma_f32_16x16x32_bf16(a_mid[rt][1], B.h1, acc, 0, 0, 0);
            acc = __builtin_amdgcn_mfma_f32_16x16x32_bf16(a_hi[rt][0],  B.l0, acc, 0, 0, 0);
            acc = __builtin_amdgcn_mfma_f32_16x16x32_bf16(a_hi[rt][1],  B.l1, acc, 0, 0, 0);
            acc = __builtin_amdgcn_mfma_f32_16x16x32_bf16(a_lo[rt][0],  B.h0, acc, 0, 0, 0);
            acc = __builtin_amdgcn_mfma_f32_16x16x32_bf16(a_lo[rt][1],  B.h1, acc, 0, 0, 0);
            acc = __builtin_amdgcn_mfma_f32_16x16x32_bf16(a_mid[rt][0], B.m0, acc, 0, 0, 0);
            acc = __builtin_amdgcn_mfma_f32_16x16x32_bf16(a_mid[rt][1], B.m1, acc, 0, 0, 0);
            #pragma unroll
            for (int q = 0; q < 4; ++q) {
                // dist = rn(rn(xx+ee) - 2*dot): *(-2) is exact, same value
                float t1 = __fadd_rn(xxv[rt][q], B.ev);
                float di = fmaf(acc[q], -2.f, t1);
                int idx = ct * 16 + col;
                if (di < bD[rt][q]) { bD[rt][q] = di; bI[rt][q] = idx; }
            }
        }
    };

    Bfrag b0, b1;
    loadB(0, b0);
    for (int ct = 0; ct < NE / 16; ct += 2) {
        loadB(ct + 1, b1);              // prefetch next while computing cur
        computeTile(b0, ct);
        if (ct + 2 < NE / 16) loadB(ct + 2, b0);
        computeTile(b1, ct + 1);
    }

    // cross-lane argmin over the 16 col-classes in each row-group
    #pragma unroll
    for (int rt = 0; rt < 4; ++rt) {
        #pragma unroll
        for (int q = 0; q < 4; ++q) {
            float d = bD[rt][q]; int i = bI[rt][q];
            #pragma unroll
            for (int off = 1; off < 16; off <<= 1) {
                float od = __shfl_xor(d, off, 64);
                int   oi = __shfl_xor(i, off, 64);
                if (od < d || (od == d && oi < i)) { d = od; i = oi; }
            }
            if (col == 0) bestI[r0 + rt * 16 + grp * 4 + q] = i;
        }
    }
}

// -------- gather winning code, write transposed out, accumulate loss --------
__global__ __launch_bounds__(BLK) void vq_out(
    const float* __restrict__ x, const float* __restrict__ embed,
    const int* __restrict__ bestI, float* __restrict__ out,
    double* __restrict__ lossAcc)
{
    __shared__ float partial[BLK / 64];
    const int t = threadIdx.x;
    const int r = blockIdx.x * BLK + t;
    const int bi = bestI[r];
    const int b = r >> 12, hw = r & (HWSZ - 1);
    const float* xb = x   + (size_t)b * (DD * HWSZ) + hw;
    float*       ob = out + (size_t)b * (DD * HWSZ) + hw;
    const float4* eq = (const float4*)(embed + (size_t)bi * DD);

    float lsum = 0.f;
    #pragma unroll
    for (int c4 = 0; c4 < DD / 4; ++c4) {
        float4 q = eq[c4];
        float qa[4] = {q.x, q.y, q.z, q.w};
        #pragma unroll
        for (int i2 = 0; i2 < 4; ++i2) {
            int c = c4 * 4 + i2;
            float xv = xb[(size_t)c * HWSZ];
            ob[(size_t)c * HWSZ] = qa[i2];
            float f = qa[i2] - xv;
            lsum = fmaf(f, f, lsum);
        }
    }
    for (int off = 32; off > 0; off >>= 1) lsum += __shfl_down(lsum, off, 64);
    if ((t & 63) == 0) partial[t >> 6] = lsum;
    __syncthreads();
    if (t == 0) {
        float tot = 0.f;
        #pragma unroll
        for (int w = 0; w < BLK / 64; ++w) tot += partial[w];
        atomicAdd(lossAcc, (double)tot);
    }
}

// -------- fallback single kernel (small ws) ---------------------------------
__global__ __launch_bounds__(BLK) void vq_main_single(
    const float* __restrict__ x, const float* __restrict__ embed,
    const float* __restrict__ e2, float* __restrict__ out,
    double* __restrict__ lossAcc)
{
    __shared__ float lds_e[KTILE * DD];
    const int t   = threadIdx.x;
    const int b   = blockIdx.x >> 3;
    const int hw0 = (blockIdx.x & 7) * (2 * BLK);
    const float* xb = x + (size_t)b * (DD * HWSZ);
    const int hwa = hw0 + t, hwb = hw0 + t + BLK;

    float xr0[DD], xr1[DD];
    float xx0 = 0.f, xx1 = 0.f;
    #pragma unroll
    for (int c = 0; c < DD; ++c) {
        float v0 = xb[(size_t)c * HWSZ + hwa];
        float v1 = xb[(size_t)c * HWSZ + hwb];
        xr0[c] = v0; xr1[c] = v1;
        xx0 = __fadd_rn(xx0, __fmul_rn(v0, v0));
        xx1 = __fadd_rn(xx1, __fmul_rn(v1, v1));
    }
    float best0 = 3.4e38f, best1 = 3.4e38f;
    int bi0 = 0, bi1 = 0;
    for (int k0 = 0; k0 < NE; k0 += KTILE) {
        __syncthreads();
        const float4* src = reinterpret_cast<const float4*>(embed + k0 * DD);
        float4* dst = reinterpret_cast<float4*>(lds_e);
        #pragma unroll
        for (int j = 0; j < (KTILE * DD / 4) / BLK; ++j)
            dst[t + j * BLK] = src[t + j * BLK];
        __syncthreads();
        for (int c = 0; c < KTILE; ++c) {
            float ee = e2[k0 + c];
            const float* ev = &lds_e[c * DD];
            float a0 = 0.f, a1 = 0.f;
            #pragma unroll
            for (int d = 0; d < DD; ++d) {
                float e = ev[d];
                a0 = fmaf(e, xr0[d], a0);
                a1 = fmaf(e, xr1[d], a1);
            }
            float di0 = __fadd_rn(__fadd_rn(xx0, ee), -2.f * a0);
            float di1 = __fadd_rn(__fadd_rn(xx1, ee), -2.f * a1);
            int kk = k0 + c;
            if (di0 < best0) { best0 = di0; bi0 = kk; }
            if (di1 < best1) { best1 = di1; bi1 = kk; }
        }
    }
    float lsum = 0.f;
    {
        const float4* eq0 = reinterpret_cast<const float4*>(embed + bi0 * DD);
        const float4* eq1 = reinterpret_cast<const float4*>(embed + bi1 * DD);
        float* ob = out + (size_t)b * (DD * HWSZ);
        #pragma unroll
        for (int c4 = 0; c4 < DD / 4; ++c4) {
            float4 q0 = eq0[c4];
            float4 q1 = eq1[c4];
            float q0a[4] = {q0.x, q0.y, q0.z, q0.w};
            float q1a[4] = {q1.x, q1.y, q1.z, q1.w};
            #pragma unroll
            for (int i = 0; i < 4; ++i) {
                int c = c4 * 4 + i;
                ob[(size_t)c * HWSZ + hwa] = q0a[i];
                ob[(size_t)c * HWSZ + hwb] = q1a[i];
                float f0 = q0a[i] - xr0[c];
                float f1 = q1a[i] - xr1[c];
                lsum = fmaf(f0, f0, lsum);
                lsum = fmaf(f1, f1, lsum);
            }
        }
    }
    for (int off = 32; off > 0; off >>= 1)
        lsum += __shfl_down(lsum, off, 64);
    __syncthreads();
    if ((t & 63) == 0) lds_e[t >> 6] = lsum;
    __syncthreads();
    if (t == 0) {
        float tot = lds_e[0] + lds_e[1] + lds_e[2] + lds_e[3];
        atomicAdd(lossAcc, (double)tot);
    }
}

// -------- finalize ----------------------------------------------------------
__global__ void vq_fin(const double* __restrict__ acc, float* __restrict__ out) {
    out[NELEM] = (float)(1.25 * (*acc) / (double)NELEM);
}

extern "C" void kernel_launch(void* const* d_in, const int* in_sizes, int n_in,
                              void* d_out, int out_size, void* d_ws, size_t ws_size,
                              hipStream_t stream) {
    const float* x     = (const float*)d_in[0];
    const float* embed = (const float*)d_in[1];
    float* out = (float*)d_out;

    double* acc  = (double*)((char*)d_ws + WS_ACC);
    float*  ee   = (float*)((char*)d_ws + WS_EE);
    ushort* ehi  = (ushort*)((char*)d_ws + WS_EHI);
    ushort* emid = (ushort*)((char*)d_ws + WS_EMID);
    ushort* elo  = (ushort*)((char*)d_ws + WS_ELO);
    float*  xxw  = (float*)((char*)d_ws + WS_XX);
    int*    bIw  = (int*)((char*)d_ws + WS_BI);

    if (ws_size >= WS_NEED) {
        vq_init2<<<(NE + BLK - 1) / BLK, BLK, 0, stream>>>(embed, ee, ehi, emid, elo, acc);
        vq_xx<<<NROW / BLK, BLK, 0, stream>>>(x, xxw);
        vq_dist_mfma<<<NROW / 256, BLK, 0, stream>>>(x, ehi, emid, elo, ee, xxw, bIw);
        vq_out<<<NROW / BLK, BLK, 0, stream>>>(x, embed, bIw, out, acc);
    } else {
        vq_init2<<<(NE + BLK - 1) / BLK, BLK, 0, stream>>>(embed, ee, ehi, emid, elo, acc);
        vq_main_single<<<NB * (HWSZ / (2 * BLK)), BLK, 0, stream>>>(x, embed, ee, out, acc);
    }
    vq_fin<<<1, 1, 0, stream>>>(acc, out);
}